// Round 7
// baseline (645.565 us; speedup 1.0000x reference)
//
#include <hip/hip_runtime.h>

typedef float f32x4 __attribute__((ext_vector_type(4)));
typedef short bf16x8 __attribute__((ext_vector_type(8)));

// ---------- helpers ----------
__device__ __forceinline__ unsigned int pk2(float a, float b) {
    unsigned int ua = __float_as_uint(a); ua += 0x7FFFu + ((ua >> 16) & 1u);
    unsigned int ub = __float_as_uint(b); ub += 0x7FFFu + ((ub >> 16) & 1u);
    return __builtin_amdgcn_perm(ub, ua, 0x07060302u);
}
__device__ __forceinline__ unsigned short bf16_rne(float a) {
    unsigned int ua = __float_as_uint(a);
    ua += 0x7FFFu + ((ua >> 16) & 1u);
    return (unsigned short)(ua >> 16);
}
__device__ __forceinline__ float tanh_fast(float x) {
    float e = __expf(x + x);
    return 1.f - 2.f / (e + 1.f);
}
__device__ __forceinline__ f32x4 mfma16(bf16x8 a, bf16x8 b, f32x4 c) {
    return __builtin_amdgcn_mfma_f32_16x16x32_bf16(a, b, c, 0, 0, 0);
}
// async global->LDS, 16B per lane; LDS dest = wave base + lane*16
__device__ __forceinline__ void ald16(const void* g, void* l) {
    __builtin_amdgcn_global_load_lds(
        (const __attribute__((address_space(1))) unsigned int*)g,
        (__attribute__((address_space(3))) unsigned int*)l, 16, 0, 0);
}

// ---------- 1. prep: fp32->bf16 weight conversion + location conv ----------
#define Q_WIH   786432
#define Q_WHH   1572864
#define Q_QW    1703936
#define Q_X2    1720320
#define Q_X1    1736704
#define Q_BAW   1802240
#define Q_BLW   1806336
#define Q_EB    1806464
#define NCVT    7057

__global__ __launch_bounds__(256) void k_prep(
    const float* __restrict__ Wih, const float* __restrict__ Whh,
    const float* __restrict__ qw, const float* __restrict__ rnn_state,
    const float* __restrict__ memory, const float* __restrict__ context,
    const float* __restrict__ aw, const float* __restrict__ lw,
    const float* __restrict__ ab, const float* __restrict__ lb,
    const float* __restrict__ atten, const float* __restrict__ convw,
    unsigned short* __restrict__ Wihb, unsigned short* __restrict__ Whhb,
    unsigned short* __restrict__ qwb, unsigned short* __restrict__ X2b,
    unsigned short* __restrict__ X1b, unsigned short* __restrict__ Bbig,
    float* __restrict__ ebias, unsigned short* __restrict__ Lconv)
{
    __shared__ float att_s[2 * 160];
    __shared__ float cw_s[1984];
    const int tid = threadIdx.x;
    if (blockIdx.x < NCVT) {
        int q = blockIdx.x * 256 + tid;
        if (q >= Q_EB) return;
        if (q < Q_WIH) {
            int i = q * 4;
            float4 v = *(const float4*)(Wih + i);
            uint2 u; u.x = pk2(v.x, v.y); u.y = pk2(v.z, v.w);
            *(uint2*)(Wihb + i) = u;
        } else if (q < Q_WHH) {
            int i = (q - Q_WIH) * 4;
            float4 v = *(const float4*)(Whh + i);
            uint2 u; u.x = pk2(v.x, v.y); u.y = pk2(v.z, v.w);
            *(uint2*)(Whhb + i) = u;
        } else if (q < Q_QW) {
            int i = (q - Q_WHH) * 4;
            float4 v = *(const float4*)(qw + i);
            uint2 u; u.x = pk2(v.x, v.y); u.y = pk2(v.z, v.w);
            *(uint2*)(qwb + i) = u;
        } else if (q < Q_X2) {
            int i = (q - Q_QW) * 4;
            float4 v = *(const float4*)(rnn_state + i);
            uint2 u; u.x = pk2(v.x, v.y); u.y = pk2(v.z, v.w);
            *(uint2*)(X2b + i) = u;
        } else if (q < Q_X1) {
            int i = (q - Q_X2) * 4;
            int b = i >> 10, c = i & 1023;
            const float* s = (c < 512) ? (memory + b * 512 + c) : (context + b * 512 + (c - 512));
            float4 v = *(const float4*)s;
            uint2 u; u.x = pk2(v.x, v.y); u.y = pk2(v.z, v.w);
            *(uint2*)(X1b + i) = u;
        } else if (q < Q_BAW) {
            int i = (q - Q_X1) * 4;
            int a = i >> 9, c = i & 511;
            float4 v = *(const float4*)(aw + a * 512 + c);
            uint2 u; u.x = pk2(v.x, v.y); u.y = pk2(v.z, v.w);
            *(uint2*)(Bbig + a * 544 + c) = u;
        } else if (q < Q_BLW) {
            int i = (q - Q_BAW) * 4;
            int a = i >> 5, c = i & 31;
            float4 v = *(const float4*)(lw + a * 32 + c);
            uint2 u; u.x = pk2(v.x, v.y); u.y = pk2(v.z, v.w);
            *(uint2*)(Bbig + a * 544 + 512 + c) = u;
        } else {
            int i = (q - Q_BLW) * 4;
            float4 va = *(const float4*)(ab + i);
            float4 vb = *(const float4*)(lb + i);
            float4 r; r.x = va.x + vb.x; r.y = va.y + vb.y; r.z = va.z + vb.z; r.w = va.w + vb.w;
            *(float4*)(ebias + i) = r;
        }
    } else {
        const int bid = blockIdx.x - NCVT;
        const int b = bid >> 3;
        const int tbase = (bid & 7) * 128;
        for (int i = tid; i < 320; i += 256) {
            int c = i / 160, j = i % 160;
            float v = 0.f;
            int pos = tbase - 15 + j;
            if (j < 158 && pos >= 0 && pos < 1024) v = atten[b * 2048 + c * 1024 + pos];
            att_s[c * 160 + j] = v;
        }
        for (int i = tid; i < 1984; i += 256) cw_s[i] = convw[i];
        __syncthreads();
        const int f = tid & 31, tq = tid >> 5;
        float acc[16];
#pragma unroll
        for (int i = 0; i < 16; ++i) acc[i] = 0.f;
        for (int c = 0; c < 2; ++c) {
            for (int k = 0; k < 31; ++k) {
                float w = cw_s[f * 62 + c * 31 + k];
                int base = c * 160 + tq * 16 + k;
#pragma unroll
                for (int ti = 0; ti < 16; ++ti) acc[ti] += w * att_s[base + ti];
            }
        }
#pragma unroll
        for (int ti = 0; ti < 16; ++ti) {
            int t = tbase + tq * 16 + ti;
            Lconv[(b * 1024 + t) * 32 + f] = bf16_rne(acc[ti]);
        }
    }
}

// ---------- 2. M=64 K-split GEMM, N-tile 128: C[ks][64][N] partial = A @ B^T ----------
__global__ __launch_bounds__(256, 4) void k_gemm_ks(
    const unsigned short* __restrict__ A1, const unsigned short* __restrict__ A2,
    const unsigned short* __restrict__ B1, const unsigned short* __restrict__ B2,
    float* __restrict__ C, int N, int nTiles, int n_split, int K, int Klen)
{
    __shared__ __align__(16) unsigned short As[64 * 32];
    __shared__ __align__(16) unsigned short Bs[128 * 32];
    const int tid = threadIdx.x;
    const int nb = blockIdx.x % nTiles;
    const int ks = blockIdx.x / nTiles;
    const int nBase = nb * 128;
    const bool use2 = nBase >= n_split;
    const unsigned short* A = use2 ? A2 : A1;
    const unsigned short* B = use2 ? B2 : B1;
    const int brow0 = nBase - (use2 ? n_split : 0);
    const int lane = tid & 63, w = tid >> 6;
    const int c = lane & 15, qd = lane >> 4;
    const int lr = lane >> 2;
    const int swzl = ((lane & 3) ^ ((lr >> 1) & 3)) * 8;

    const f32x4 fz = {0.f, 0.f, 0.f, 0.f};
    f32x4 acc[4][2];
#pragma unroll
    for (int i = 0; i < 4; ++i) { acc[i][0] = fz; acc[i][1] = fz; }

    const int k0b = ks * Klen;
    const int nkc = Klen >> 5;
    for (int kc = 0; kc < nkc; ++kc) {
        const int k0 = k0b + kc * 32;
        ald16(A + (size_t)(w * 16 + lr) * K + k0 + swzl, &As[w * 512]);
        ald16(B + (size_t)(brow0 + w * 16 + lr) * K + k0 + swzl, &Bs[w * 512]);
        ald16(B + (size_t)(brow0 + 64 + w * 16 + lr) * K + k0 + swzl, &Bs[2048 + w * 512]);
        __syncthreads();
        const int rdoff = (qd ^ ((c >> 1) & 3)) * 8;
        bf16x8 af[4];
#pragma unroll
        for (int i = 0; i < 4; ++i) af[i] = *(const bf16x8*)&As[(i * 16 + c) * 32 + rdoff];
#pragma unroll
        for (int j = 0; j < 2; ++j) {
            bf16x8 bj = *(const bf16x8*)&Bs[(w * 32 + j * 16 + c) * 32 + rdoff];
#pragma unroll
            for (int i = 0; i < 4; ++i) acc[i][j] = mfma16(af[i], bj, acc[i][j]);
        }
        __syncthreads();
    }
    float* Cp = C + (size_t)ks * 64 * N;
#pragma unroll
    for (int i = 0; i < 4; ++i)
#pragma unroll
        for (int r = 0; r < 4; ++r) {
            int row = i * 16 + qd * 4 + r;
#pragma unroll
            for (int j = 0; j < 2; ++j) {
                int col = nBase + w * 32 + j * 16 + c;
                Cp[row * N + col] = acc[i][j][r];
            }
        }
}

// ---------- 3. GRU gates (sums K-split partials, adds biases) ----------
__global__ __launch_bounds__(256) void k_gates(
    const float* __restrict__ Cg, const float* __restrict__ h0,
    const float* __restrict__ bih, const float* __restrict__ bhh,
    float* __restrict__ outv, unsigned short* __restrict__ X3b)
{
    int idx = blockIdx.x * 256 + threadIdx.x;
    int b = idx >> 10, h = idx & 1023;
    const float* g0 = Cg + b * 6144;
    const float* g1 = Cg + 393216 + b * 6144;
    float ir = g0[h] + g1[h] + bih[h];
    float iz = g0[h + 1024] + g1[h + 1024] + bih[h + 1024];
    float inn = g0[h + 2048] + g1[h + 2048] + bih[h + 2048];
    float hr = g0[h + 3072] + g1[h + 3072] + bhh[h];
    float hz = g0[h + 4096] + g1[h + 4096] + bhh[h + 1024];
    float hn = g0[h + 5120] + g1[h + 5120] + bhh[h + 2048];
    float r = 1.f / (1.f + __expf(-(ir + hr)));
    float z = 1.f / (1.f + __expf(-(iz + hz)));
    float n = tanh_fast(inn + r * hn);
    float o = (1.f - z) * n + z * h0[idx];
    outv[idx] = o;
    X3b[idx] = bf16_rne(o);
}

// ---------- 4. energy GEMM, M=256 x N=512, fused tanh/v-dot ----------
// v8: TRAFFIC reduction, not scheduling. R1-R6 showed k_attn pinned at >=99us
// for all schedules; bytes/CU accounting (680KB/block x 4 blocks/CU at ~11.5
// B/cyc/CU return BW) matches 99us exactly -> per-CU delivery-bound. Fix:
// M=256 per block (grid=256 = 1 block/CU) so Bbig (544KB) is pulled ONCE per
// CU instead of 4x. Inner loop / swizzles / 2-phase dbuf + __syncthreads are
// the R2-proven pattern, just scaled: 16 waves, wave (wm,wn) owns 64x128 via
// acc[4][8]; 2 ald16/wave/iter stage B; A-convert spread over 1024 threads.
__global__ __launch_bounds__(1024, 4) void k_attn(
    const float* __restrict__ annots, const unsigned short* __restrict__ Lconv,
    const unsigned short* __restrict__ Bbig, const float* __restrict__ pqP,
    const float* __restrict__ qb, const float* __restrict__ ebias,
    const float* __restrict__ vw, float* __restrict__ wsal)
{
    __shared__ __align__(16) unsigned short As[2][256 * 32];   // 32 KB
    __shared__ __align__(16) unsigned short Bs[2][512 * 32];   // 64 KB
    __shared__ float red[16][64];                              //  4 KB
    const int tid = threadIdx.x;
    const int btBase = blockIdx.x * 256;
    const int b = btBase >> 10;
    const int lane = tid & 63, w = tid >> 6;      // 16 waves
    const int wm = w & 3, wn = w >> 2;            // row-band (64), col-quarter (128)
    const int c = lane & 15, qd = lane >> 4;
    const int lr = lane >> 2;
    const int swzl = ((lane & 3) ^ ((lr >> 1) & 3)) * 8;
    const int arow = tid >> 2, alc = tid & 3;     // A-convert: 256 rows x 4 thr
    const int apofs = (alc ^ ((arow >> 1) & 3)) * 8;
    const int rdoff = (qd ^ ((c >> 1) & 3)) * 8;

    const f32x4 fz = {0.f, 0.f, 0.f, 0.f};
    f32x4 acc[4][8];
#pragma unroll
    for (int i = 0; i < 4; ++i)
#pragma unroll
        for (int j = 0; j < 8; ++j) acc[i][j] = fz;

    // per-thread source bases
    const float* aP = annots + (size_t)(btBase + arow) * 512 + alc * 8;
    const unsigned short* bP = Bbig + (size_t)(w * 32 + lr) * 544 + swzl;

    // ---- prologue: stage tile 0 ----
    ald16(bP, &Bs[0][(w * 32) * 32]);
    ald16(bP + 16 * 544, &Bs[0][(w * 32 + 16) * 32]);
    {
        float4 v0 = *(const float4*)(aP);
        float4 v1 = *(const float4*)(aP + 4);
        uint4 u;
        u.x = pk2(v0.x, v0.y); u.y = pk2(v0.z, v0.w);
        u.z = pk2(v1.x, v1.y); u.w = pk2(v1.z, v1.w);
        *(uint4*)&As[0][arow * 32 + apofs] = u;
    }
    __syncthreads();

    for (int kc = 0; kc < 17; ++kc) {
        const int cur = kc & 1, nxt = cur ^ 1;
        // ---- stage next B tile (2 x ald16 per wave, dbuf)
        if (kc < 16) {
            const int k1 = (kc + 1) * 32;
            ald16(bP + k1, &Bs[nxt][(w * 32) * 32]);
            ald16(bP + 16 * 544 + k1, &Bs[nxt][(w * 32 + 16) * 32]);
        }
        // ---- prefetch next A to regs (kc<15) or stage Lconv tail (kc==15)
        float4 v0n, v1n;
        if (kc < 15) {
            v0n = *(const float4*)(aP + (kc + 1) * 32);
            v1n = *(const float4*)(aP + (kc + 1) * 32 + 4);
        } else if (kc == 15) {
            ald16(Lconv + (size_t)(btBase + w * 16 + lr) * 32 + swzl, &As[nxt][w * 512]);
        }
        // ---- compute current tile
        bf16x8 af[4];
#pragma unroll
        for (int i = 0; i < 4; ++i)
            af[i] = *(const bf16x8*)&As[cur][(wm * 64 + i * 16 + c) * 32 + rdoff];
        __builtin_amdgcn_s_setprio(1);
#pragma unroll
        for (int j = 0; j < 8; ++j) {
            bf16x8 bj = *(const bf16x8*)&Bs[cur][(wn * 128 + j * 16 + c) * 32 + rdoff];
#pragma unroll
            for (int i = 0; i < 4; ++i) acc[i][j] = mfma16(af[i], bj, acc[i][j]);
        }
        __builtin_amdgcn_s_setprio(0);
        // ---- write-late next A, then barrier (drains staging loads)
        if (kc < 16) {
            if (kc < 15) {
                uint4 u;
                u.x = pk2(v0n.x, v0n.y); u.y = pk2(v0n.z, v0n.w);
                u.z = pk2(v1n.x, v1n.y); u.w = pk2(v1n.z, v1n.w);
                *(uint4*)&As[nxt][arow * 32 + apofs] = u;
            }
            __syncthreads();
        }
    }
    // epilogue: raw_align[t] = sum_col v[col]*tanh(acc + pq[b][col] + qb + ebias)
    float pe[8], vv[8];
#pragma unroll
    for (int j = 0; j < 8; ++j) {
        int colg = wn * 128 + j * 16 + c;
        float s = qb[colg] + ebias[colg];
#pragma unroll
        for (int p = 0; p < 8; ++p) s += pqP[p * 32768 + b * 512 + colg];
        pe[j] = s;
        vv[j] = vw[colg];
    }
#pragma unroll
    for (int i = 0; i < 4; ++i)
#pragma unroll
        for (int r = 0; r < 4; ++r) {
            float p = 0.f;
#pragma unroll
            for (int j = 0; j < 8; ++j)
                p += vv[j] * tanh_fast(acc[i][j][r] + pe[j]);
            p += __shfl_xor(p, 1);
            p += __shfl_xor(p, 2);
            p += __shfl_xor(p, 4);
            p += __shfl_xor(p, 8);
            if (c == 0) red[w][i * 16 + qd * 4 + r] = p;
        }
    __syncthreads();
    if (tid < 256) {
        const int band = tid >> 6, idx = tid & 63;
        wsal[btBase + band * 64 + idx] =
            red[band][idx] + red[band + 4][idx] + red[band + 8][idx] + red[band + 12][idx];
    }
}

// ---------- 5. normalize + context ----------
__global__ __launch_bounds__(256) void k_ctx(
    const float* __restrict__ annots, const float* __restrict__ wsal,
    const int* __restrict__ mask, float* __restrict__ out)
{
    __shared__ float al[1024];
    __shared__ float wsum[4];
    __shared__ float red[256];
    const int b = blockIdx.x >> 3;
    const int chunk = blockIdx.x & 7;
    const int tid = threadIdx.x;
    float lsum = 0.f;
#pragma unroll
    for (int p = 0; p < 4; ++p) {
        int t = p * 256 + tid;
        int bt = b * 1024 + t;
        float raw = wsal[bt];
        float s = (mask[bt] != 0) ? 1.f / (1.f + __expf(-raw)) : 0.f;
        al[t] = s;
        lsum += s;
    }
    for (int off = 32; off > 0; off >>= 1) lsum += __shfl_xor(lsum, off);
    if ((tid & 63) == 0) wsum[tid >> 6] = lsum;
    __syncthreads();
    const float tot = wsum[0] + wsum[1] + wsum[2] + wsum[3];
    const float inv = 1.f / tot;
    if (chunk == 0) {
#pragma unroll
        for (int p = 0; p < 4; ++p) {
            int t = p * 256 + tid;
            out[98304 + b * 1024 + t] = al[t] * inv;
        }
    }
    const int dq = tid & 63, tq = tid >> 6;
    const int d = chunk * 64 + dq;
    const float* ap = annots + (size_t)(b * 1024 + tq * 256) * 512 + d;
    const float* alp = al + tq * 256;
    float s0 = 0.f, s1 = 0.f, s2 = 0.f, s3 = 0.f;
#pragma unroll 4
    for (int t = 0; t < 256; t += 4) {
        s0 += alp[t]     * ap[(size_t)(t)     * 512];
        s1 += alp[t + 1] * ap[(size_t)(t + 1) * 512];
        s2 += alp[t + 2] * ap[(size_t)(t + 2) * 512];
        s3 += alp[t + 3] * ap[(size_t)(t + 3) * 512];
    }
    red[tid] = (s0 + s1) + (s2 + s3);
    __syncthreads();
    if (tid < 64) {
        float s2r = red[tid] + red[64 + tid] + red[128 + tid] + red[192 + tid];
        out[65536 + b * 512 + chunk * 64 + tid] = s2r * inv;
    }
}

extern "C" void kernel_launch(void* const* d_in, const int* in_sizes, int n_in,
                              void* d_out, int out_size, void* d_ws, size_t ws_size,
                              hipStream_t stream) {
    const float* memory    = (const float*)d_in[0];
    const float* context   = (const float*)d_in[1];
    const float* rnn_state = (const float*)d_in[2];
    const float* annots    = (const float*)d_in[3];
    const float* atten     = (const float*)d_in[4];
    const int*   mask      = (const int*)d_in[5];
    const float* W_ih   = (const float*)d_in[7];
    const float* W_hh   = (const float*)d_in[8];
    const float* b_ih   = (const float*)d_in[9];
    const float* b_hh   = (const float*)d_in[10];
    const float* conv_w = (const float*)d_in[11];
    const float* loc_w  = (const float*)d_in[12];
    const float* loc_b  = (const float*)d_in[13];
    const float* q_w    = (const float*)d_in[14];
    const float* q_b    = (const float*)d_in[15];
    const float* a_w    = (const float*)d_in[16];
    const float* a_b    = (const float*)d_in[17];
    const float* v_w    = (const float*)d_in[18];
    float* out = (float*)d_out;

    char* w8 = (char*)d_ws;
    unsigned short* Lconv = (unsigned short*)(w8 + 0);         //  4,194,304
    unsigned short* Bbig  = (unsigned short*)(w8 + 4194304);   //    557,056
    unsigned short* Wihb  = (unsigned short*)(w8 + 4751360);   //  6,291,456
    unsigned short* Whhb  = (unsigned short*)(w8 + 11042816);  //  6,291,456
    unsigned short* qwb   = (unsigned short*)(w8 + 17334272);  //  1,048,576
    unsigned short* X1b   = (unsigned short*)(w8 + 18382848);  //    131,072
    unsigned short* X2b   = (unsigned short*)(w8 + 18513920);  //    131,072
    unsigned short* X3b   = (unsigned short*)(w8 + 18644992);  //    131,072
    float*          Cgru  = (float*)(w8 + 18776064);           //  3,145,728 (2 K-split partials)
    // pq partials (8) + wsal alias the (dead-after-k_gates) Cgru region:
    float*          pqP   = (float*)(w8 + 18776064);           //  1,048,576 (8 partials)
    float*          wsal  = (float*)(w8 + 19824640);           //    262,144
    float*          ebias = (float*)(w8 + 21921792);           //      2,048

    k_prep<<<NCVT + 512, 256, 0, stream>>>(W_ih, W_hh, q_w, rnn_state, memory, context,
                                           a_w, loc_w, a_b, loc_b, atten, conv_w,
                                           Wihb, Whhb, qwb, X2b, X1b, Bbig, ebias, Lconv);
    // GRU: N=6144 (gi|gh), 48 N-tiles x K-split2 = 96 blocks
    k_gemm_ks<<<96, 256, 0, stream>>>(X1b, X2b, Wihb, Whhb, Cgru, 6144, 48, 3072, 1024, 512);
    k_gates<<<256, 256, 0, stream>>>(Cgru, rnn_state, b_ih, b_hh, out, X3b);
    // pq: N=512, 4 N-tiles x K-split8 (Klen=128) = 32 blocks
    k_gemm_ks<<<32, 256, 0, stream>>>(X3b, X3b, qwb, qwb, pqP, 512, 4, 0x40000000, 1024, 128);
    // energy: M=256 per block, 256 blocks = 1/CU
    k_attn<<<256, 1024, 0, stream>>>(annots, Lconv, Bbig, pqP, q_b, ebias, v_w, wsal);
    k_ctx<<<512, 256, 0, stream>>>(annots, wsal, mask, out);
}

// Round 8
// 346.432 us; speedup vs baseline: 1.8635x; 1.8635x over previous
//
#include <hip/hip_runtime.h>

typedef float f32x4 __attribute__((ext_vector_type(4)));
typedef short bf16x8 __attribute__((ext_vector_type(8)));

// ---------- helpers ----------
__device__ __forceinline__ unsigned int pk2(float a, float b) {
    unsigned int ua = __float_as_uint(a); ua += 0x7FFFu + ((ua >> 16) & 1u);
    unsigned int ub = __float_as_uint(b); ub += 0x7FFFu + ((ub >> 16) & 1u);
    return __builtin_amdgcn_perm(ub, ua, 0x07060302u);
}
__device__ __forceinline__ unsigned short bf16_rne(float a) {
    unsigned int ua = __float_as_uint(a);
    ua += 0x7FFFu + ((ua >> 16) & 1u);
    return (unsigned short)(ua >> 16);
}
__device__ __forceinline__ float tanh_fast(float x) {
    float e = __expf(x + x);
    return 1.f - 2.f / (e + 1.f);
}
__device__ __forceinline__ f32x4 mfma16(bf16x8 a, bf16x8 b, f32x4 c) {
    return __builtin_amdgcn_mfma_f32_16x16x32_bf16(a, b, c, 0, 0, 0);
}
// async global->LDS, 16B per lane; LDS dest = wave base + lane*16
__device__ __forceinline__ void ald16(const void* g, void* l) {
    __builtin_amdgcn_global_load_lds(
        (const __attribute__((address_space(1))) unsigned int*)g,
        (__attribute__((address_space(3))) unsigned int*)l, 16, 0, 0);
}

// ---------- 1. prep: fp32->bf16 weight conversion + location conv ----------
#define Q_WIH   786432
#define Q_WHH   1572864
#define Q_QW    1703936
#define Q_X2    1720320
#define Q_X1    1736704
#define Q_BAW   1802240
#define Q_BLW   1806336
#define Q_EB    1806464
#define NCVT    7057

__global__ __launch_bounds__(256) void k_prep(
    const float* __restrict__ Wih, const float* __restrict__ Whh,
    const float* __restrict__ qw, const float* __restrict__ rnn_state,
    const float* __restrict__ memory, const float* __restrict__ context,
    const float* __restrict__ aw, const float* __restrict__ lw,
    const float* __restrict__ ab, const float* __restrict__ lb,
    const float* __restrict__ atten, const float* __restrict__ convw,
    unsigned short* __restrict__ Wihb, unsigned short* __restrict__ Whhb,
    unsigned short* __restrict__ qwb, unsigned short* __restrict__ X2b,
    unsigned short* __restrict__ X1b, unsigned short* __restrict__ Bbig,
    float* __restrict__ ebias, unsigned short* __restrict__ Lconv)
{
    __shared__ float att_s[2 * 160];
    __shared__ float cw_s[1984];
    const int tid = threadIdx.x;
    if (blockIdx.x < NCVT) {
        int q = blockIdx.x * 256 + tid;
        if (q >= Q_EB) return;
        if (q < Q_WIH) {
            int i = q * 4;
            float4 v = *(const float4*)(Wih + i);
            uint2 u; u.x = pk2(v.x, v.y); u.y = pk2(v.z, v.w);
            *(uint2*)(Wihb + i) = u;
        } else if (q < Q_WHH) {
            int i = (q - Q_WIH) * 4;
            float4 v = *(const float4*)(Whh + i);
            uint2 u; u.x = pk2(v.x, v.y); u.y = pk2(v.z, v.w);
            *(uint2*)(Whhb + i) = u;
        } else if (q < Q_QW) {
            int i = (q - Q_WHH) * 4;
            float4 v = *(const float4*)(qw + i);
            uint2 u; u.x = pk2(v.x, v.y); u.y = pk2(v.z, v.w);
            *(uint2*)(qwb + i) = u;
        } else if (q < Q_X2) {
            int i = (q - Q_QW) * 4;
            float4 v = *(const float4*)(rnn_state + i);
            uint2 u; u.x = pk2(v.x, v.y); u.y = pk2(v.z, v.w);
            *(uint2*)(X2b + i) = u;
        } else if (q < Q_X1) {
            int i = (q - Q_X2) * 4;
            int b = i >> 10, c = i & 1023;
            const float* s = (c < 512) ? (memory + b * 512 + c) : (context + b * 512 + (c - 512));
            float4 v = *(const float4*)s;
            uint2 u; u.x = pk2(v.x, v.y); u.y = pk2(v.z, v.w);
            *(uint2*)(X1b + i) = u;
        } else if (q < Q_BAW) {
            int i = (q - Q_X1) * 4;
            int a = i >> 9, c = i & 511;
            float4 v = *(const float4*)(aw + a * 512 + c);
            uint2 u; u.x = pk2(v.x, v.y); u.y = pk2(v.z, v.w);
            *(uint2*)(Bbig + a * 544 + c) = u;
        } else if (q < Q_BLW) {
            int i = (q - Q_BAW) * 4;
            int a = i >> 5, c = i & 31;
            float4 v = *(const float4*)(lw + a * 32 + c);
            uint2 u; u.x = pk2(v.x, v.y); u.y = pk2(v.z, v.w);
            *(uint2*)(Bbig + a * 544 + 512 + c) = u;
        } else {
            int i = (q - Q_BLW) * 4;
            float4 va = *(const float4*)(ab + i);
            float4 vb = *(const float4*)(lb + i);
            float4 r; r.x = va.x + vb.x; r.y = va.y + vb.y; r.z = va.z + vb.z; r.w = va.w + vb.w;
            *(float4*)(ebias + i) = r;
        }
    } else {
        const int bid = blockIdx.x - NCVT;
        const int b = bid >> 3;
        const int tbase = (bid & 7) * 128;
        for (int i = tid; i < 320; i += 256) {
            int c = i / 160, j = i % 160;
            float v = 0.f;
            int pos = tbase - 15 + j;
            if (j < 158 && pos >= 0 && pos < 1024) v = atten[b * 2048 + c * 1024 + pos];
            att_s[c * 160 + j] = v;
        }
        for (int i = tid; i < 1984; i += 256) cw_s[i] = convw[i];
        __syncthreads();
        const int f = tid & 31, tq = tid >> 5;
        float acc[16];
#pragma unroll
        for (int i = 0; i < 16; ++i) acc[i] = 0.f;
        for (int c = 0; c < 2; ++c) {
            for (int k = 0; k < 31; ++k) {
                float w = cw_s[f * 62 + c * 31 + k];
                int base = c * 160 + tq * 16 + k;
#pragma unroll
                for (int ti = 0; ti < 16; ++ti) acc[ti] += w * att_s[base + ti];
            }
        }
#pragma unroll
        for (int ti = 0; ti < 16; ++ti) {
            int t = tbase + tq * 16 + ti;
            Lconv[(b * 1024 + t) * 32 + f] = bf16_rne(acc[ti]);
        }
    }
}

// ---------- 2. M=64 K-split GEMM, N-tile 128: C[ks][64][N] partial = A @ B^T ----------
__global__ __launch_bounds__(256, 4) void k_gemm_ks(
    const unsigned short* __restrict__ A1, const unsigned short* __restrict__ A2,
    const unsigned short* __restrict__ B1, const unsigned short* __restrict__ B2,
    float* __restrict__ C, int N, int nTiles, int n_split, int K, int Klen)
{
    __shared__ __align__(16) unsigned short As[64 * 32];
    __shared__ __align__(16) unsigned short Bs[128 * 32];
    const int tid = threadIdx.x;
    const int nb = blockIdx.x % nTiles;
    const int ks = blockIdx.x / nTiles;
    const int nBase = nb * 128;
    const bool use2 = nBase >= n_split;
    const unsigned short* A = use2 ? A2 : A1;
    const unsigned short* B = use2 ? B2 : B1;
    const int brow0 = nBase - (use2 ? n_split : 0);
    const int lane = tid & 63, w = tid >> 6;
    const int c = lane & 15, qd = lane >> 4;
    const int lr = lane >> 2;
    const int swzl = ((lane & 3) ^ ((lr >> 1) & 3)) * 8;

    const f32x4 fz = {0.f, 0.f, 0.f, 0.f};
    f32x4 acc[4][2];
#pragma unroll
    for (int i = 0; i < 4; ++i) { acc[i][0] = fz; acc[i][1] = fz; }

    const int k0b = ks * Klen;
    const int nkc = Klen >> 5;
    for (int kc = 0; kc < nkc; ++kc) {
        const int k0 = k0b + kc * 32;
        ald16(A + (size_t)(w * 16 + lr) * K + k0 + swzl, &As[w * 512]);
        ald16(B + (size_t)(brow0 + w * 16 + lr) * K + k0 + swzl, &Bs[w * 512]);
        ald16(B + (size_t)(brow0 + 64 + w * 16 + lr) * K + k0 + swzl, &Bs[2048 + w * 512]);
        __syncthreads();
        const int rdoff = (qd ^ ((c >> 1) & 3)) * 8;
        bf16x8 af[4];
#pragma unroll
        for (int i = 0; i < 4; ++i) af[i] = *(const bf16x8*)&As[(i * 16 + c) * 32 + rdoff];
#pragma unroll
        for (int j = 0; j < 2; ++j) {
            bf16x8 bj = *(const bf16x8*)&Bs[(w * 32 + j * 16 + c) * 32 + rdoff];
#pragma unroll
            for (int i = 0; i < 4; ++i) acc[i][j] = mfma16(af[i], bj, acc[i][j]);
        }
        __syncthreads();
    }
    float* Cp = C + (size_t)ks * 64 * N;
#pragma unroll
    for (int i = 0; i < 4; ++i)
#pragma unroll
        for (int r = 0; r < 4; ++r) {
            int row = i * 16 + qd * 4 + r;
#pragma unroll
            for (int j = 0; j < 2; ++j) {
                int col = nBase + w * 32 + j * 16 + c;
                Cp[row * N + col] = acc[i][j][r];
            }
        }
}

// ---------- 3. GRU gates (sums K-split partials, adds biases) ----------
__global__ __launch_bounds__(256) void k_gates(
    const float* __restrict__ Cg, const float* __restrict__ h0,
    const float* __restrict__ bih, const float* __restrict__ bhh,
    float* __restrict__ outv, unsigned short* __restrict__ X3b)
{
    int idx = blockIdx.x * 256 + threadIdx.x;
    int b = idx >> 10, h = idx & 1023;
    const float* g0 = Cg + b * 6144;
    const float* g1 = Cg + 393216 + b * 6144;
    float ir = g0[h] + g1[h] + bih[h];
    float iz = g0[h + 1024] + g1[h + 1024] + bih[h + 1024];
    float inn = g0[h + 2048] + g1[h + 2048] + bih[h + 2048];
    float hr = g0[h + 3072] + g1[h + 3072] + bhh[h];
    float hz = g0[h + 4096] + g1[h + 4096] + bhh[h + 1024];
    float hn = g0[h + 5120] + g1[h + 5120] + bhh[h + 2048];
    float r = 1.f / (1.f + __expf(-(ir + hr)));
    float z = 1.f / (1.f + __expf(-(iz + hz)));
    float n = tanh_fast(inn + r * hn);
    float o = (1.f - z) * n + z * h0[idx];
    outv[idx] = o;
    X3b[idx] = bf16_rne(o);
}

// ---------- 4. energy GEMM, M=64 x N=512, fused tanh/v-dot ----------
// v10 = R2's proven 99us kernel + DEPTH-2 annots prefetch: loads for tile k+2
// are issued at the top of iteration k (right after the barrier) and consumed
// at the write-late of iteration k+1 -> every annots load has a full
// iteration (~5-7k cyc) in flight before any wait touches it. Everything
// else (B staging, swizzles, barrier placement) is bit-identical to R2.
__global__ __launch_bounds__(256, 2) void k_attn(
    const float* __restrict__ annots, const unsigned short* __restrict__ Lconv,
    const unsigned short* __restrict__ Bbig, const float* __restrict__ pqP,
    const float* __restrict__ qb, const float* __restrict__ ebias,
    const float* __restrict__ vw, float* __restrict__ wsal)
{
    __shared__ __align__(16) unsigned short As[2][64 * 32];    //  8 KB
    __shared__ __align__(16) unsigned short Bs[2][512 * 32];   // 64 KB
    __shared__ float red[4][64];
    const int tid = threadIdx.x;
    const int btBase = blockIdx.x * 64;
    const int b = btBase >> 10;
    const int lane = tid & 63, w = tid >> 6;
    const int c = lane & 15, qd = lane >> 4;
    const int lr = lane >> 2;
    const int swzl = ((lane & 3) ^ ((lr >> 1) & 3)) * 8;
    const int arow = tid >> 2, alc = tid & 3;
    const int apofs = (alc ^ ((arow >> 1) & 3)) * 8;
    const int rdoff = (qd ^ ((c >> 1) & 3)) * 8;

    const f32x4 fz = {0.f, 0.f, 0.f, 0.f};
    f32x4 acc[4][8];
#pragma unroll
    for (int i = 0; i < 4; ++i)
#pragma unroll
        for (int j = 0; j < 8; ++j) acc[i][j] = fz;

    // per-thread source bases
    const float* aP = annots + (size_t)(btBase + arow) * 512 + alc * 8;
    const unsigned short* bP = Bbig + (size_t)(w * 16 + lr) * 544 + swzl;

    // ---- prologue: stage tile 0; preload annots for tile 1 (avC) ----
#pragma unroll
    for (int s = 0; s < 8; ++s)
        ald16(bP + (size_t)s * 64 * 544, &Bs[0][s * 2048 + w * 512]);
    {
        float4 v0 = *(const float4*)(aP);
        float4 v1 = *(const float4*)(aP + 4);
        uint4 u;
        u.x = pk2(v0.x, v0.y); u.y = pk2(v0.z, v0.w);
        u.z = pk2(v1.x, v1.y); u.w = pk2(v1.z, v1.w);
        *(uint4*)&As[0][arow * 32 + apofs] = u;
    }
    float4 avC0 = *(const float4*)(aP + 32);   // annots for tile 1
    float4 avC1 = *(const float4*)(aP + 36);
    __syncthreads();

    for (int kc = 0; kc < 17; ++kc) {
        const int cur = kc & 1, nxt = cur ^ 1;
        // ---- issue annots loads for tile kc+2 (consumed NEXT iteration)
        float4 f0, f1;
        if (kc <= 13) {
            f0 = *(const float4*)(aP + (kc + 2) * 32);
            f1 = *(const float4*)(aP + (kc + 2) * 32 + 4);
        }
        // ---- stage next B tile (dbuf); Lconv tail at kc==15
        if (kc < 16) {
            const int k1 = (kc + 1) * 32;
#pragma unroll
            for (int s = 0; s < 8; ++s)
                ald16(bP + (size_t)s * 64 * 544 + k1, &Bs[nxt][s * 2048 + w * 512]);
            if (kc == 15)
                ald16(Lconv + (size_t)(btBase + w * 16 + lr) * 32 + swzl, &As[nxt][w * 512]);
        }
        // ---- compute current tile
        bf16x8 af[4];
#pragma unroll
        for (int i = 0; i < 4; ++i) af[i] = *(const bf16x8*)&As[cur][(i * 16 + c) * 32 + rdoff];
        __builtin_amdgcn_s_setprio(1);
#pragma unroll
        for (int j = 0; j < 8; ++j) {
            bf16x8 bj = *(const bf16x8*)&Bs[cur][(w * 128 + j * 16 + c) * 32 + rdoff];
#pragma unroll
            for (int i = 0; i < 4; ++i) acc[i][j] = mfma16(af[i], bj, acc[i][j]);
        }
        __builtin_amdgcn_s_setprio(0);
        // ---- write-late: convert avC (annots tile kc+1, loaded LAST iter)
        if (kc <= 14) {
            uint4 u;
            u.x = pk2(avC0.x, avC0.y); u.y = pk2(avC0.z, avC0.w);
            u.z = pk2(avC1.x, avC1.y); u.w = pk2(avC1.z, avC1.w);
            *(uint4*)&As[nxt][arow * 32 + apofs] = u;
        }
        if (kc <= 13) { avC0 = f0; avC1 = f1; }
        if (kc < 16) __syncthreads();
    }
    // epilogue: raw_align[t] = sum_col v[col]*tanh(acc + pq[b][col] + qb + ebias)
    float pe[8], vv[8];
#pragma unroll
    for (int j = 0; j < 8; ++j) {
        int colg = w * 128 + j * 16 + c;
        float s = qb[colg] + ebias[colg];
#pragma unroll
        for (int p = 0; p < 8; ++p) s += pqP[p * 32768 + b * 512 + colg];
        pe[j] = s;
        vv[j] = vw[colg];
    }
#pragma unroll
    for (int i = 0; i < 4; ++i)
#pragma unroll
        for (int r = 0; r < 4; ++r) {
            float p = 0.f;
#pragma unroll
            for (int j = 0; j < 8; ++j)
                p += vv[j] * tanh_fast(acc[i][j][r] + pe[j]);
            p += __shfl_xor(p, 1);
            p += __shfl_xor(p, 2);
            p += __shfl_xor(p, 4);
            p += __shfl_xor(p, 8);
            if (c == 0) red[w][i * 16 + qd * 4 + r] = p;
        }
    __syncthreads();
    if (tid < 64)
        wsal[btBase + tid] = red[0][tid] + red[1][tid] + red[2][tid] + red[3][tid];
}

// ---------- 5a. context partials: row-major coalesced annots stream ----------
// block = (b, tc): sums s[t]*annots[b,t,:] over its 128-t chunk into ctxP.
// Reads annots ROWS as float4 (2KB/wave-instr group) instead of k_ctx's old
// 4B-stride-2KB column walk.
__global__ __launch_bounds__(256) void k_ctxA(
    const float* __restrict__ annots, const float* __restrict__ wsal,
    const int* __restrict__ mask, float* __restrict__ ctxP)
{
    __shared__ float cx[4][512];
    const int b = blockIdx.x >> 3;
    const int tc = blockIdx.x & 7;
    const int tid = threadIdx.x, lane = tid & 63, wv = tid >> 6;
    const int t0 = tc * 128 + wv * 32;
    const float* wp = wsal + b * 1024;
    const int* mp = mask + b * 1024;
    const float* ap = annots + (size_t)(b * 1024 + t0) * 512 + lane * 4;

    float a0 = 0.f, a1 = 0.f, a2 = 0.f, a3 = 0.f;
    float a4 = 0.f, a5 = 0.f, a6 = 0.f, a7 = 0.f;
#pragma unroll 4
    for (int r = 0; r < 32; ++r) {
        int t = t0 + r;
        float raw = wp[t];
        float s = (mp[t] != 0) ? 1.f / (1.f + __expf(-raw)) : 0.f;
        float4 va = *(const float4*)(ap + (size_t)r * 512);
        float4 vb = *(const float4*)(ap + (size_t)r * 512 + 256);
        a0 += s * va.x; a1 += s * va.y; a2 += s * va.z; a3 += s * va.w;
        a4 += s * vb.x; a5 += s * vb.y; a6 += s * vb.z; a7 += s * vb.w;
    }
    cx[wv][lane * 4 + 0] = a0; cx[wv][lane * 4 + 1] = a1;
    cx[wv][lane * 4 + 2] = a2; cx[wv][lane * 4 + 3] = a3;
    cx[wv][256 + lane * 4 + 0] = a4; cx[wv][256 + lane * 4 + 1] = a5;
    cx[wv][256 + lane * 4 + 2] = a6; cx[wv][256 + lane * 4 + 3] = a7;
    __syncthreads();
    float* cp = ctxP + (size_t)(tc * 64 + b) * 512;
    cp[tid]       = cx[0][tid]       + cx[1][tid]       + cx[2][tid]       + cx[3][tid];
    cp[tid + 256] = cx[0][tid + 256] + cx[1][tid + 256] + cx[2][tid + 256] + cx[3][tid + 256];
}

// ---------- 5b. normalize: alignment out + context reduce ----------
__global__ __launch_bounds__(256) void k_ctxB(
    const float* __restrict__ wsal, const int* __restrict__ mask,
    const float* __restrict__ ctxP, float* __restrict__ out)
{
    __shared__ float sv[1024];
    __shared__ float wsum[4];
    const int b = blockIdx.x;
    const int tid = threadIdx.x;
    float lsum = 0.f;
#pragma unroll
    for (int p = 0; p < 4; ++p) {
        int t = p * 256 + tid;
        int bt = b * 1024 + t;
        float raw = wsal[bt];
        float s = (mask[bt] != 0) ? 1.f / (1.f + __expf(-raw)) : 0.f;
        sv[t] = s;
        lsum += s;
    }
    for (int off = 32; off > 0; off >>= 1) lsum += __shfl_xor(lsum, off);
    if ((tid & 63) == 0) wsum[tid >> 6] = lsum;
    __syncthreads();
    const float tot = wsum[0] + wsum[1] + wsum[2] + wsum[3];
    const float inv = 1.f / tot;
#pragma unroll
    for (int p = 0; p < 4; ++p) {
        int t = p * 256 + tid;
        out[98304 + b * 1024 + t] = sv[t] * inv;
    }
#pragma unroll
    for (int h = 0; h < 2; ++h) {
        int d = h * 256 + tid;
        float csum = 0.f;
#pragma unroll
        for (int tc = 0; tc < 8; ++tc)
            csum += ctxP[(size_t)(tc * 64 + b) * 512 + d];
        out[65536 + b * 512 + d] = csum * inv;
    }
}

extern "C" void kernel_launch(void* const* d_in, const int* in_sizes, int n_in,
                              void* d_out, int out_size, void* d_ws, size_t ws_size,
                              hipStream_t stream) {
    const float* memory    = (const float*)d_in[0];
    const float* context   = (const float*)d_in[1];
    const float* rnn_state = (const float*)d_in[2];
    const float* annots    = (const float*)d_in[3];
    const float* atten     = (const float*)d_in[4];
    const int*   mask      = (const int*)d_in[5];
    const float* W_ih   = (const float*)d_in[7];
    const float* W_hh   = (const float*)d_in[8];
    const float* b_ih   = (const float*)d_in[9];
    const float* b_hh   = (const float*)d_in[10];
    const float* conv_w = (const float*)d_in[11];
    const float* loc_w  = (const float*)d_in[12];
    const float* loc_b  = (const float*)d_in[13];
    const float* q_w    = (const float*)d_in[14];
    const float* q_b    = (const float*)d_in[15];
    const float* a_w    = (const float*)d_in[16];
    const float* a_b    = (const float*)d_in[17];
    const float* v_w    = (const float*)d_in[18];
    float* out = (float*)d_out;

    char* w8 = (char*)d_ws;
    unsigned short* Lconv = (unsigned short*)(w8 + 0);         //  4,194,304
    unsigned short* Bbig  = (unsigned short*)(w8 + 4194304);   //    557,056
    unsigned short* Wihb  = (unsigned short*)(w8 + 4751360);   //  6,291,456
    unsigned short* Whhb  = (unsigned short*)(w8 + 11042816);  //  6,291,456
    unsigned short* qwb   = (unsigned short*)(w8 + 17334272);  //  1,048,576
    unsigned short* X1b   = (unsigned short*)(w8 + 18382848);  //    131,072
    unsigned short* X2b   = (unsigned short*)(w8 + 18513920);  //    131,072
    unsigned short* X3b   = (unsigned short*)(w8 + 18644992);  //    131,072
    float*          Cgru  = (float*)(w8 + 18776064);           //  3,145,728 (2 K-split partials)
    // pq partials (8) alias the (dead-after-k_gates) Cgru region; ctxP then
    // aliases pqP (dead after k_attn's epilogue) — stream-ordered reuse.
    float*          pqP   = (float*)(w8 + 18776064);           //  1,048,576 (8 partials)
    float*          ctxP  = (float*)(w8 + 18776064);           //  1,048,576 (8 partials)
    float*          wsal  = (float*)(w8 + 19824640);           //    262,144
    float*          ebias = (float*)(w8 + 21921792);           //      2,048

    k_prep<<<NCVT + 512, 256, 0, stream>>>(W_ih, W_hh, q_w, rnn_state, memory, context,
                                           a_w, loc_w, a_b, loc_b, atten, conv_w,
                                           Wihb, Whhb, qwb, X2b, X1b, Bbig, ebias, Lconv);
    // GRU: N=6144 (gi|gh), 48 N-tiles x K-split2 = 96 blocks
    k_gemm_ks<<<96, 256, 0, stream>>>(X1b, X2b, Wihb, Whhb, Cgru, 6144, 48, 3072, 1024, 512);
    k_gates<<<256, 256, 0, stream>>>(Cgru, rnn_state, b_ih, b_hh, out, X3b);
    // pq: N=512, 4 N-tiles x K-split8 (Klen=128) = 32 blocks
    k_gemm_ks<<<32, 256, 0, stream>>>(X3b, X3b, qwb, qwb, pqP, 512, 4, 0x40000000, 1024, 128);
    k_attn<<<1024, 256, 0, stream>>>(annots, Lconv, Bbig, pqP, q_b, ebias, v_w, wsal);
    k_ctxA<<<512, 256, 0, stream>>>(annots, wsal, mask, ctxP);
    k_ctxB<<<64, 256, 0, stream>>>(wsal, mask, ctxP, out);
}

// Round 9
// 345.940 us; speedup vs baseline: 1.8661x; 1.0014x over previous
//
#include <hip/hip_runtime.h>

typedef float f32x4 __attribute__((ext_vector_type(4)));
typedef short bf16x8 __attribute__((ext_vector_type(8)));

// ---------- helpers ----------
__device__ __forceinline__ unsigned int pk2(float a, float b) {
    unsigned int ua = __float_as_uint(a); ua += 0x7FFFu + ((ua >> 16) & 1u);
    unsigned int ub = __float_as_uint(b); ub += 0x7FFFu + ((ub >> 16) & 1u);
    return __builtin_amdgcn_perm(ub, ua, 0x07060302u);
}
__device__ __forceinline__ unsigned short bf16_rne(float a) {
    unsigned int ua = __float_as_uint(a);
    ua += 0x7FFFu + ((ua >> 16) & 1u);
    return (unsigned short)(ua >> 16);
}
__device__ __forceinline__ float tanh_fast(float x) {
    float e = __expf(x + x);
    return 1.f - 2.f / (e + 1.f);
}
__device__ __forceinline__ f32x4 mfma16(bf16x8 a, bf16x8 b, f32x4 c) {
    return __builtin_amdgcn_mfma_f32_16x16x32_bf16(a, b, c, 0, 0, 0);
}
// async global->LDS, 16B per lane; LDS dest = wave base + lane*16
__device__ __forceinline__ void ald16(const void* g, void* l) {
    __builtin_amdgcn_global_load_lds(
        (const __attribute__((address_space(1))) unsigned int*)g,
        (__attribute__((address_space(3))) unsigned int*)l, 16, 0, 0);
}

// ---------- 1. prep: fp32->bf16 weight conversion + location conv ----------
#define Q_WIH   786432
#define Q_WHH   1572864
#define Q_QW    1703936
#define Q_X2    1720320
#define Q_X1    1736704
#define Q_BAW   1802240
#define Q_BLW   1806336
#define Q_EB    1806464
#define NCVT    7057

__global__ __launch_bounds__(256) void k_prep(
    const float* __restrict__ Wih, const float* __restrict__ Whh,
    const float* __restrict__ qw, const float* __restrict__ rnn_state,
    const float* __restrict__ memory, const float* __restrict__ context,
    const float* __restrict__ aw, const float* __restrict__ lw,
    const float* __restrict__ ab, const float* __restrict__ lb,
    const float* __restrict__ atten, const float* __restrict__ convw,
    unsigned short* __restrict__ Wihb, unsigned short* __restrict__ Whhb,
    unsigned short* __restrict__ qwb, unsigned short* __restrict__ X2b,
    unsigned short* __restrict__ X1b, unsigned short* __restrict__ Bbig,
    float* __restrict__ ebias, unsigned short* __restrict__ Lconv)
{
    __shared__ float att_s[2 * 160];
    __shared__ float cw_s[1984];
    const int tid = threadIdx.x;
    if (blockIdx.x < NCVT) {
        int q = blockIdx.x * 256 + tid;
        if (q >= Q_EB) return;
        if (q < Q_WIH) {
            int i = q * 4;
            float4 v = *(const float4*)(Wih + i);
            uint2 u; u.x = pk2(v.x, v.y); u.y = pk2(v.z, v.w);
            *(uint2*)(Wihb + i) = u;
        } else if (q < Q_WHH) {
            int i = (q - Q_WIH) * 4;
            float4 v = *(const float4*)(Whh + i);
            uint2 u; u.x = pk2(v.x, v.y); u.y = pk2(v.z, v.w);
            *(uint2*)(Whhb + i) = u;
        } else if (q < Q_QW) {
            int i = (q - Q_WHH) * 4;
            float4 v = *(const float4*)(qw + i);
            uint2 u; u.x = pk2(v.x, v.y); u.y = pk2(v.z, v.w);
            *(uint2*)(qwb + i) = u;
        } else if (q < Q_X2) {
            int i = (q - Q_QW) * 4;
            float4 v = *(const float4*)(rnn_state + i);
            uint2 u; u.x = pk2(v.x, v.y); u.y = pk2(v.z, v.w);
            *(uint2*)(X2b + i) = u;
        } else if (q < Q_X1) {
            int i = (q - Q_X2) * 4;
            int b = i >> 10, c = i & 1023;
            const float* s = (c < 512) ? (memory + b * 512 + c) : (context + b * 512 + (c - 512));
            float4 v = *(const float4*)s;
            uint2 u; u.x = pk2(v.x, v.y); u.y = pk2(v.z, v.w);
            *(uint2*)(X1b + i) = u;
        } else if (q < Q_BAW) {
            int i = (q - Q_X1) * 4;
            int a = i >> 9, c = i & 511;
            float4 v = *(const float4*)(aw + a * 512 + c);
            uint2 u; u.x = pk2(v.x, v.y); u.y = pk2(v.z, v.w);
            *(uint2*)(Bbig + a * 544 + c) = u;
        } else if (q < Q_BLW) {
            int i = (q - Q_BAW) * 4;
            int a = i >> 5, c = i & 31;
            float4 v = *(const float4*)(lw + a * 32 + c);
            uint2 u; u.x = pk2(v.x, v.y); u.y = pk2(v.z, v.w);
            *(uint2*)(Bbig + a * 544 + 512 + c) = u;
        } else {
            int i = (q - Q_BLW) * 4;
            float4 va = *(const float4*)(ab + i);
            float4 vb = *(const float4*)(lb + i);
            float4 r; r.x = va.x + vb.x; r.y = va.y + vb.y; r.z = va.z + vb.z; r.w = va.w + vb.w;
            *(float4*)(ebias + i) = r;
        }
    } else {
        const int bid = blockIdx.x - NCVT;
        const int b = bid >> 3;
        const int tbase = (bid & 7) * 128;
        for (int i = tid; i < 320; i += 256) {
            int c = i / 160, j = i % 160;
            float v = 0.f;
            int pos = tbase - 15 + j;
            if (j < 158 && pos >= 0 && pos < 1024) v = atten[b * 2048 + c * 1024 + pos];
            att_s[c * 160 + j] = v;
        }
        for (int i = tid; i < 1984; i += 256) cw_s[i] = convw[i];
        __syncthreads();
        const int f = tid & 31, tq = tid >> 5;
        float acc[16];
#pragma unroll
        for (int i = 0; i < 16; ++i) acc[i] = 0.f;
        for (int c = 0; c < 2; ++c) {
            for (int k = 0; k < 31; ++k) {
                float w = cw_s[f * 62 + c * 31 + k];
                int base = c * 160 + tq * 16 + k;
#pragma unroll
                for (int ti = 0; ti < 16; ++ti) acc[ti] += w * att_s[base + ti];
            }
        }
#pragma unroll
        for (int ti = 0; ti < 16; ++ti) {
            int t = tbase + tq * 16 + ti;
            Lconv[(b * 1024 + t) * 32 + f] = bf16_rne(acc[ti]);
        }
    }
}

// ---------- 2. M=64 K-split GEMM, N-tile 128: C[ks][64][N] partial = A @ B^T ----------
__global__ __launch_bounds__(256, 4) void k_gemm_ks(
    const unsigned short* __restrict__ A1, const unsigned short* __restrict__ A2,
    const unsigned short* __restrict__ B1, const unsigned short* __restrict__ B2,
    float* __restrict__ C, int N, int nTiles, int n_split, int K, int Klen)
{
    __shared__ __align__(16) unsigned short As[64 * 32];
    __shared__ __align__(16) unsigned short Bs[128 * 32];
    const int tid = threadIdx.x;
    const int nb = blockIdx.x % nTiles;
    const int ks = blockIdx.x / nTiles;
    const int nBase = nb * 128;
    const bool use2 = nBase >= n_split;
    const unsigned short* A = use2 ? A2 : A1;
    const unsigned short* B = use2 ? B2 : B1;
    const int brow0 = nBase - (use2 ? n_split : 0);
    const int lane = tid & 63, w = tid >> 6;
    const int c = lane & 15, qd = lane >> 4;
    const int lr = lane >> 2;
    const int swzl = ((lane & 3) ^ ((lr >> 1) & 3)) * 8;

    const f32x4 fz = {0.f, 0.f, 0.f, 0.f};
    f32x4 acc[4][2];
#pragma unroll
    for (int i = 0; i < 4; ++i) { acc[i][0] = fz; acc[i][1] = fz; }

    const int k0b = ks * Klen;
    const int nkc = Klen >> 5;
    for (int kc = 0; kc < nkc; ++kc) {
        const int k0 = k0b + kc * 32;
        ald16(A + (size_t)(w * 16 + lr) * K + k0 + swzl, &As[w * 512]);
        ald16(B + (size_t)(brow0 + w * 16 + lr) * K + k0 + swzl, &Bs[w * 512]);
        ald16(B + (size_t)(brow0 + 64 + w * 16 + lr) * K + k0 + swzl, &Bs[2048 + w * 512]);
        __syncthreads();
        const int rdoff = (qd ^ ((c >> 1) & 3)) * 8;
        bf16x8 af[4];
#pragma unroll
        for (int i = 0; i < 4; ++i) af[i] = *(const bf16x8*)&As[(i * 16 + c) * 32 + rdoff];
#pragma unroll
        for (int j = 0; j < 2; ++j) {
            bf16x8 bj = *(const bf16x8*)&Bs[(w * 32 + j * 16 + c) * 32 + rdoff];
#pragma unroll
            for (int i = 0; i < 4; ++i) acc[i][j] = mfma16(af[i], bj, acc[i][j]);
        }
        __syncthreads();
    }
    float* Cp = C + (size_t)ks * 64 * N;
#pragma unroll
    for (int i = 0; i < 4; ++i)
#pragma unroll
        for (int r = 0; r < 4; ++r) {
            int row = i * 16 + qd * 4 + r;
#pragma unroll
            for (int j = 0; j < 2; ++j) {
                int col = nBase + w * 32 + j * 16 + c;
                Cp[row * N + col] = acc[i][j][r];
            }
        }
}

// ---------- 3. GRU gates (sums K-split partials, adds biases) ----------
__global__ __launch_bounds__(256) void k_gates(
    const float* __restrict__ Cg, const float* __restrict__ h0,
    const float* __restrict__ bih, const float* __restrict__ bhh,
    float* __restrict__ outv, unsigned short* __restrict__ X3b)
{
    int idx = blockIdx.x * 256 + threadIdx.x;
    int b = idx >> 10, h = idx & 1023;
    const float* g0 = Cg + b * 6144;
    const float* g1 = Cg + 393216 + b * 6144;
    float ir = g0[h] + g1[h] + bih[h];
    float iz = g0[h + 1024] + g1[h + 1024] + bih[h + 1024];
    float inn = g0[h + 2048] + g1[h + 2048] + bih[h + 2048];
    float hr = g0[h + 3072] + g1[h + 3072] + bhh[h];
    float hz = g0[h + 4096] + g1[h + 4096] + bhh[h + 1024];
    float hn = g0[h + 5120] + g1[h + 5120] + bhh[h + 2048];
    float r = 1.f / (1.f + __expf(-(ir + hr)));
    float z = 1.f / (1.f + __expf(-(iz + hz)));
    float n = tanh_fast(inn + r * hn);
    float o = (1.f - z) * n + z * h0[idx];
    outv[idx] = o;
    X3b[idx] = bf16_rne(o);
}

// ---------- 4. energy GEMM, M=64 x N=512, fused tanh/v-dot ----------
// EXACT revert to the Round-2-measured 99.2us kernel: 2-phase double-buffered
// pipeline, stage tile k+1 at top of iteration k, annots prefetched to regs
// in-iteration, converted+written to LDS AFTER the MFMA cluster (write-late),
// ONE __syncthreads per iteration. pq epilogue = 2 K-split partials.
__global__ __launch_bounds__(256, 2) void k_attn(
    const float* __restrict__ annots, const unsigned short* __restrict__ Lconv,
    const unsigned short* __restrict__ Bbig, const float* __restrict__ pqP,
    const float* __restrict__ qb, const float* __restrict__ ebias,
    const float* __restrict__ vw, float* __restrict__ wsal)
{
    __shared__ __align__(16) unsigned short As[2][64 * 32];    //  8 KB
    __shared__ __align__(16) unsigned short Bs[2][512 * 32];   // 64 KB
    __shared__ float red[4][64];
    const int tid = threadIdx.x;
    const int btBase = blockIdx.x * 64;
    const int b = btBase >> 10;
    const int lane = tid & 63, w = tid >> 6;
    const int c = lane & 15, qd = lane >> 4;
    const int lr = lane >> 2;
    const int swzl = ((lane & 3) ^ ((lr >> 1) & 3)) * 8;
    const int arow = tid >> 2, alc = tid & 3;
    const int apofs = (alc ^ ((arow >> 1) & 3)) * 8;

    const f32x4 fz = {0.f, 0.f, 0.f, 0.f};
    f32x4 acc[4][8];
#pragma unroll
    for (int i = 0; i < 4; ++i)
#pragma unroll
        for (int j = 0; j < 8; ++j) acc[i][j] = fz;

    // per-thread source bases
    const float* aP = annots + (size_t)(btBase + arow) * 512 + alc * 8;
    const unsigned short* bP = Bbig + (size_t)(w * 16 + lr) * 544 + swzl;

    // ---- prologue: stage tile 0 into buffer 0 ----
#pragma unroll
    for (int s = 0; s < 8; ++s)
        ald16(bP + (size_t)s * 64 * 544, &Bs[0][s * 2048 + w * 512]);
    {
        float4 v0 = *(const float4*)(aP);
        float4 v1 = *(const float4*)(aP + 4);
        uint4 u;
        u.x = pk2(v0.x, v0.y); u.y = pk2(v0.z, v0.w);
        u.z = pk2(v1.x, v1.y); u.w = pk2(v1.z, v1.w);
        *(uint4*)&As[0][arow * 32 + apofs] = u;
    }
    __syncthreads();

    for (int kc = 0; kc < 17; ++kc) {
        const int cur = kc & 1, nxt = cur ^ 1;
        float4 v0n, v1n;
        // ---- issue next tile's loads (latency hides under this tile's compute)
        if (kc < 16) {
            const int k1 = (kc + 1) * 32;
#pragma unroll
            for (int s = 0; s < 8; ++s)
                ald16(bP + (size_t)s * 64 * 544 + k1, &Bs[nxt][s * 2048 + w * 512]);
            if (kc < 15) {
                v0n = *(const float4*)(aP + k1);
                v1n = *(const float4*)(aP + k1 + 4);
            } else {
                ald16(Lconv + (size_t)(btBase + w * 16 + lr) * 32 + swzl, &As[nxt][w * 512]);
            }
        }
        // ---- compute current tile
        const int rdoff = (qd ^ ((c >> 1) & 3)) * 8;
        bf16x8 af[4];
#pragma unroll
        for (int i = 0; i < 4; ++i) af[i] = *(const bf16x8*)&As[cur][(i * 16 + c) * 32 + rdoff];
        __builtin_amdgcn_s_setprio(1);
#pragma unroll
        for (int j = 0; j < 8; ++j) {
            bf16x8 bj = *(const bf16x8*)&Bs[cur][(w * 128 + j * 16 + c) * 32 + rdoff];
#pragma unroll
            for (int i = 0; i < 4; ++i) acc[i][j] = mfma16(af[i], bj, acc[i][j]);
        }
        __builtin_amdgcn_s_setprio(0);
        // ---- write-late: convert prefetched annots into As[nxt], then ONE barrier
        if (kc < 16) {
            if (kc < 15) {
                uint4 u;
                u.x = pk2(v0n.x, v0n.y); u.y = pk2(v0n.z, v0n.w);
                u.z = pk2(v1n.x, v1n.y); u.w = pk2(v1n.z, v1n.w);
                *(uint4*)&As[nxt][arow * 32 + apofs] = u;
            }
            __syncthreads();
        }
    }
    // epilogue: raw_align[t] = sum_col v[col]*tanh(acc + pq[b][col] + qb + ebias)
    float pe[8], vv[8];
#pragma unroll
    for (int j = 0; j < 8; ++j) {
        int colg = w * 128 + j * 16 + c;
        pe[j] = pqP[b * 512 + colg] + pqP[32768 + b * 512 + colg] + qb[colg] + ebias[colg];
        vv[j] = vw[colg];
    }
#pragma unroll
    for (int i = 0; i < 4; ++i)
#pragma unroll
        for (int r = 0; r < 4; ++r) {
            float p = 0.f;
#pragma unroll
            for (int j = 0; j < 8; ++j)
                p += vv[j] * tanh_fast(acc[i][j][r] + pe[j]);
            p += __shfl_xor(p, 1);
            p += __shfl_xor(p, 2);
            p += __shfl_xor(p, 4);
            p += __shfl_xor(p, 8);
            if (c == 0) red[w][i * 16 + qd * 4 + r] = p;
        }
    __syncthreads();
    if (tid < 64)
        wsal[btBase + tid] = red[0][tid] + red[1][tid] + red[2][tid] + red[3][tid];
}

// ---------- 5a. context partials: row-major coalesced annots stream ----------
__global__ __launch_bounds__(256) void k_ctxA(
    const float* __restrict__ annots, const float* __restrict__ wsal,
    const int* __restrict__ mask, float* __restrict__ ctxP)
{
    __shared__ float cx[4][512];
    const int b = blockIdx.x >> 3;
    const int tc = blockIdx.x & 7;
    const int tid = threadIdx.x, lane = tid & 63, wv = tid >> 6;
    const int t0 = tc * 128 + wv * 32;
    const float* wp = wsal + b * 1024;
    const int* mp = mask + b * 1024;
    const float* ap = annots + (size_t)(b * 1024 + t0) * 512 + lane * 4;

    float a0 = 0.f, a1 = 0.f, a2 = 0.f, a3 = 0.f;
    float a4 = 0.f, a5 = 0.f, a6 = 0.f, a7 = 0.f;
#pragma unroll 4
    for (int r = 0; r < 32; ++r) {
        int t = t0 + r;
        float raw = wp[t];
        float s = (mp[t] != 0) ? 1.f / (1.f + __expf(-raw)) : 0.f;
        float4 va = *(const float4*)(ap + (size_t)r * 512);
        float4 vb = *(const float4*)(ap + (size_t)r * 512 + 256);
        a0 += s * va.x; a1 += s * va.y; a2 += s * va.z; a3 += s * va.w;
        a4 += s * vb.x; a5 += s * vb.y; a6 += s * vb.z; a7 += s * vb.w;
    }
    cx[wv][lane * 4 + 0] = a0; cx[wv][lane * 4 + 1] = a1;
    cx[wv][lane * 4 + 2] = a2; cx[wv][lane * 4 + 3] = a3;
    cx[wv][256 + lane * 4 + 0] = a4; cx[wv][256 + lane * 4 + 1] = a5;
    cx[wv][256 + lane * 4 + 2] = a6; cx[wv][256 + lane * 4 + 3] = a7;
    __syncthreads();
    float* cp = ctxP + (size_t)(tc * 64 + b) * 512;
    cp[tid]       = cx[0][tid]       + cx[1][tid]       + cx[2][tid]       + cx[3][tid];
    cp[tid + 256] = cx[0][tid + 256] + cx[1][tid + 256] + cx[2][tid + 256] + cx[3][tid + 256];
}

// ---------- 5b. normalize: alignment out + context reduce ----------
__global__ __launch_bounds__(256) void k_ctxB(
    const float* __restrict__ wsal, const int* __restrict__ mask,
    const float* __restrict__ ctxP, float* __restrict__ out)
{
    __shared__ float sv[1024];
    __shared__ float wsum[4];
    const int b = blockIdx.x;
    const int tid = threadIdx.x;
    float lsum = 0.f;
#pragma unroll
    for (int p = 0; p < 4; ++p) {
        int t = p * 256 + tid;
        int bt = b * 1024 + t;
        float raw = wsal[bt];
        float s = (mask[bt] != 0) ? 1.f / (1.f + __expf(-raw)) : 0.f;
        sv[t] = s;
        lsum += s;
    }
    for (int off = 32; off > 0; off >>= 1) lsum += __shfl_xor(lsum, off);
    if ((tid & 63) == 0) wsum[tid >> 6] = lsum;
    __syncthreads();
    const float tot = wsum[0] + wsum[1] + wsum[2] + wsum[3];
    const float inv = 1.f / tot;
#pragma unroll
    for (int p = 0; p < 4; ++p) {
        int t = p * 256 + tid;
        out[98304 + b * 1024 + t] = sv[t] * inv;
    }
#pragma unroll
    for (int h = 0; h < 2; ++h) {
        int d = h * 256 + tid;
        float csum = 0.f;
#pragma unroll
        for (int tc = 0; tc < 8; ++tc)
            csum += ctxP[(size_t)(tc * 64 + b) * 512 + d];
        out[65536 + b * 512 + d] = csum * inv;
    }
}

extern "C" void kernel_launch(void* const* d_in, const int* in_sizes, int n_in,
                              void* d_out, int out_size, void* d_ws, size_t ws_size,
                              hipStream_t stream) {
    const float* memory    = (const float*)d_in[0];
    const float* context   = (const float*)d_in[1];
    const float* rnn_state = (const float*)d_in[2];
    const float* annots    = (const float*)d_in[3];
    const float* atten     = (const float*)d_in[4];
    const int*   mask      = (const int*)d_in[5];
    const float* W_ih   = (const float*)d_in[7];
    const float* W_hh   = (const float*)d_in[8];
    const float* b_ih   = (const float*)d_in[9];
    const float* b_hh   = (const float*)d_in[10];
    const float* conv_w = (const float*)d_in[11];
    const float* loc_w  = (const float*)d_in[12];
    const float* loc_b  = (const float*)d_in[13];
    const float* q_w    = (const float*)d_in[14];
    const float* q_b    = (const float*)d_in[15];
    const float* a_w    = (const float*)d_in[16];
    const float* a_b    = (const float*)d_in[17];
    const float* v_w    = (const float*)d_in[18];
    float* out = (float*)d_out;

    char* w8 = (char*)d_ws;
    unsigned short* Lconv = (unsigned short*)(w8 + 0);         //  4,194,304
    unsigned short* Bbig  = (unsigned short*)(w8 + 4194304);   //    557,056
    unsigned short* Wihb  = (unsigned short*)(w8 + 4751360);   //  6,291,456
    unsigned short* Whhb  = (unsigned short*)(w8 + 11042816);  //  6,291,456
    unsigned short* qwb   = (unsigned short*)(w8 + 17334272);  //  1,048,576
    unsigned short* X1b   = (unsigned short*)(w8 + 18382848);  //    131,072
    unsigned short* X2b   = (unsigned short*)(w8 + 18513920);  //    131,072
    unsigned short* X3b   = (unsigned short*)(w8 + 18644992);  //    131,072
    float*          Cgru  = (float*)(w8 + 18776064);           //  3,145,728 (2 K-split partials)
    // pq partials + ctxP alias the (dead-after-k_gates / dead-after-k_attn)
    // Cgru region — stream-ordered reuse:
    float*          pqP   = (float*)(w8 + 18776064);           //    262,144 (2 partials)
    float*          ctxP  = (float*)(w8 + 18776064);           //  1,048,576 (8 partials)
    float*          wsal  = (float*)(w8 + 19824640);           //    262,144
    float*          ebias = (float*)(w8 + 21921792);           //      2,048

    k_prep<<<NCVT + 512, 256, 0, stream>>>(W_ih, W_hh, q_w, rnn_state, memory, context,
                                           a_w, loc_w, a_b, loc_b, atten, conv_w,
                                           Wihb, Whhb, qwb, X2b, X1b, Bbig, ebias, Lconv);
    // GRU: N=6144 (gi|gh), 48 N-tiles x K-split2 = 96 blocks
    k_gemm_ks<<<96, 256, 0, stream>>>(X1b, X2b, Wihb, Whhb, Cgru, 6144, 48, 3072, 1024, 512);
    k_gates<<<256, 256, 0, stream>>>(Cgru, rnn_state, b_ih, b_hh, out, X3b);
    // pq: N=512, 4 N-tiles x K-split2 = 8 blocks
    k_gemm_ks<<<8, 256, 0, stream>>>(X3b, X3b, qwb, qwb, pqP, 512, 4, 0x40000000, 1024, 512);
    k_attn<<<1024, 256, 0, stream>>>(annots, Lconv, Bbig, pqP, q_b, ebias, v_w, wsal);
    k_ctxA<<<512, 256, 0, stream>>>(annots, wsal, mask, ctxP);
    k_ctxB<<<64, 256, 0, stream>>>(wsal, mask, ctxP, out);
}

// Round 10
// 329.875 us; speedup vs baseline: 1.9570x; 1.0487x over previous
//
#include <hip/hip_runtime.h>

typedef float f32x4 __attribute__((ext_vector_type(4)));
typedef short bf16x8 __attribute__((ext_vector_type(8)));

// ---------- helpers ----------
__device__ __forceinline__ unsigned int pk2(float a, float b) {
    unsigned int ua = __float_as_uint(a); ua += 0x7FFFu + ((ua >> 16) & 1u);
    unsigned int ub = __float_as_uint(b); ub += 0x7FFFu + ((ub >> 16) & 1u);
    return __builtin_amdgcn_perm(ub, ua, 0x07060302u);
}
__device__ __forceinline__ unsigned short bf16_rne(float a) {
    unsigned int ua = __float_as_uint(a);
    ua += 0x7FFFu + ((ua >> 16) & 1u);
    return (unsigned short)(ua >> 16);
}
__device__ __forceinline__ float tanh_fast(float x) {
    float e = __expf(x + x);
    return 1.f - 2.f / (e + 1.f);
}
__device__ __forceinline__ f32x4 mfma16(bf16x8 a, bf16x8 b, f32x4 c) {
    return __builtin_amdgcn_mfma_f32_16x16x32_bf16(a, b, c, 0, 0, 0);
}
// async global->LDS, 16B per lane; LDS dest = wave base + lane*16
__device__ __forceinline__ void ald16(const void* g, void* l) {
    __builtin_amdgcn_global_load_lds(
        (const __attribute__((address_space(1))) unsigned int*)g,
        (__attribute__((address_space(3))) unsigned int*)l, 16, 0, 0);
}

// ---------- 1. prep: fp32->bf16 weight conversion + location conv ----------
#define Q_WIH   786432
#define Q_WHH   1572864
#define Q_QW    1703936
#define Q_X2    1720320
#define Q_X1    1736704
#define Q_BAW   1802240
#define Q_BLW   1806336
#define Q_EB    1806464
#define NCVT    7057

__global__ __launch_bounds__(256) void k_prep(
    const float* __restrict__ Wih, const float* __restrict__ Whh,
    const float* __restrict__ qw, const float* __restrict__ rnn_state,
    const float* __restrict__ memory, const float* __restrict__ context,
    const float* __restrict__ aw, const float* __restrict__ lw,
    const float* __restrict__ ab, const float* __restrict__ lb,
    const float* __restrict__ atten, const float* __restrict__ convw,
    unsigned short* __restrict__ Wihb, unsigned short* __restrict__ Whhb,
    unsigned short* __restrict__ qwb, unsigned short* __restrict__ X2b,
    unsigned short* __restrict__ X1b, unsigned short* __restrict__ Bbig,
    float* __restrict__ ebias, unsigned short* __restrict__ Lconv)
{
    __shared__ float att_s[2 * 160];
    __shared__ float cw_s[1984];
    const int tid = threadIdx.x;
    if (blockIdx.x < NCVT) {
        int q = blockIdx.x * 256 + tid;
        if (q >= Q_EB) return;
        if (q < Q_WIH) {
            int i = q * 4;
            float4 v = *(const float4*)(Wih + i);
            uint2 u; u.x = pk2(v.x, v.y); u.y = pk2(v.z, v.w);
            *(uint2*)(Wihb + i) = u;
        } else if (q < Q_WHH) {
            int i = (q - Q_WIH) * 4;
            float4 v = *(const float4*)(Whh + i);
            uint2 u; u.x = pk2(v.x, v.y); u.y = pk2(v.z, v.w);
            *(uint2*)(Whhb + i) = u;
        } else if (q < Q_QW) {
            int i = (q - Q_WHH) * 4;
            float4 v = *(const float4*)(qw + i);
            uint2 u; u.x = pk2(v.x, v.y); u.y = pk2(v.z, v.w);
            *(uint2*)(qwb + i) = u;
        } else if (q < Q_X2) {
            int i = (q - Q_QW) * 4;
            float4 v = *(const float4*)(rnn_state + i);
            uint2 u; u.x = pk2(v.x, v.y); u.y = pk2(v.z, v.w);
            *(uint2*)(X2b + i) = u;
        } else if (q < Q_X1) {
            int i = (q - Q_X2) * 4;
            int b = i >> 10, c = i & 1023;
            const float* s = (c < 512) ? (memory + b * 512 + c) : (context + b * 512 + (c - 512));
            float4 v = *(const float4*)s;
            uint2 u; u.x = pk2(v.x, v.y); u.y = pk2(v.z, v.w);
            *(uint2*)(X1b + i) = u;
        } else if (q < Q_BAW) {
            int i = (q - Q_X1) * 4;
            int a = i >> 9, c = i & 511;
            float4 v = *(const float4*)(aw + a * 512 + c);
            uint2 u; u.x = pk2(v.x, v.y); u.y = pk2(v.z, v.w);
            *(uint2*)(Bbig + a * 544 + c) = u;
        } else if (q < Q_BLW) {
            int i = (q - Q_BAW) * 4;
            int a = i >> 5, c = i & 31;
            float4 v = *(const float4*)(lw + a * 32 + c);
            uint2 u; u.x = pk2(v.x, v.y); u.y = pk2(v.z, v.w);
            *(uint2*)(Bbig + a * 544 + 512 + c) = u;
        } else {
            int i = (q - Q_BLW) * 4;
            float4 va = *(const float4*)(ab + i);
            float4 vb = *(const float4*)(lb + i);
            float4 r; r.x = va.x + vb.x; r.y = va.y + vb.y; r.z = va.z + vb.z; r.w = va.w + vb.w;
            *(float4*)(ebias + i) = r;
        }
    } else {
        const int bid = blockIdx.x - NCVT;
        const int b = bid >> 3;
        const int tbase = (bid & 7) * 128;
        for (int i = tid; i < 320; i += 256) {
            int c = i / 160, j = i % 160;
            float v = 0.f;
            int pos = tbase - 15 + j;
            if (j < 158 && pos >= 0 && pos < 1024) v = atten[b * 2048 + c * 1024 + pos];
            att_s[c * 160 + j] = v;
        }
        for (int i = tid; i < 1984; i += 256) cw_s[i] = convw[i];
        __syncthreads();
        const int f = tid & 31, tq = tid >> 5;
        float acc[16];
#pragma unroll
        for (int i = 0; i < 16; ++i) acc[i] = 0.f;
        for (int c = 0; c < 2; ++c) {
            for (int k = 0; k < 31; ++k) {
                float w = cw_s[f * 62 + c * 31 + k];
                int base = c * 160 + tq * 16 + k;
#pragma unroll
                for (int ti = 0; ti < 16; ++ti) acc[ti] += w * att_s[base + ti];
            }
        }
#pragma unroll
        for (int ti = 0; ti < 16; ++ti) {
            int t = tbase + tq * 16 + ti;
            Lconv[(b * 1024 + t) * 32 + f] = bf16_rne(acc[ti]);
        }
    }
}

// ---------- 2. M=64 K-split GEMM, N-tile 128: C[ks][64][N] partial = A @ B^T ----------
__global__ __launch_bounds__(256, 4) void k_gemm_ks(
    const unsigned short* __restrict__ A1, const unsigned short* __restrict__ A2,
    const unsigned short* __restrict__ B1, const unsigned short* __restrict__ B2,
    float* __restrict__ C, int N, int nTiles, int n_split, int K, int Klen)
{
    __shared__ __align__(16) unsigned short As[64 * 32];
    __shared__ __align__(16) unsigned short Bs[128 * 32];
    const int tid = threadIdx.x;
    const int nb = blockIdx.x % nTiles;
    const int ks = blockIdx.x / nTiles;
    const int nBase = nb * 128;
    const bool use2 = nBase >= n_split;
    const unsigned short* A = use2 ? A2 : A1;
    const unsigned short* B = use2 ? B2 : B1;
    const int brow0 = nBase - (use2 ? n_split : 0);
    const int lane = tid & 63, w = tid >> 6;
    const int c = lane & 15, qd = lane >> 4;
    const int lr = lane >> 2;
    const int swzl = ((lane & 3) ^ ((lr >> 1) & 3)) * 8;

    const f32x4 fz = {0.f, 0.f, 0.f, 0.f};
    f32x4 acc[4][2];
#pragma unroll
    for (int i = 0; i < 4; ++i) { acc[i][0] = fz; acc[i][1] = fz; }

    const int k0b = ks * Klen;
    const int nkc = Klen >> 5;
    for (int kc = 0; kc < nkc; ++kc) {
        const int k0 = k0b + kc * 32;
        ald16(A + (size_t)(w * 16 + lr) * K + k0 + swzl, &As[w * 512]);
        ald16(B + (size_t)(brow0 + w * 16 + lr) * K + k0 + swzl, &Bs[w * 512]);
        ald16(B + (size_t)(brow0 + 64 + w * 16 + lr) * K + k0 + swzl, &Bs[2048 + w * 512]);
        __syncthreads();
        const int rdoff = (qd ^ ((c >> 1) & 3)) * 8;
        bf16x8 af[4];
#pragma unroll
        for (int i = 0; i < 4; ++i) af[i] = *(const bf16x8*)&As[(i * 16 + c) * 32 + rdoff];
#pragma unroll
        for (int j = 0; j < 2; ++j) {
            bf16x8 bj = *(const bf16x8*)&Bs[(w * 32 + j * 16 + c) * 32 + rdoff];
#pragma unroll
            for (int i = 0; i < 4; ++i) acc[i][j] = mfma16(af[i], bj, acc[i][j]);
        }
        __syncthreads();
    }
    float* Cp = C + (size_t)ks * 64 * N;
#pragma unroll
    for (int i = 0; i < 4; ++i)
#pragma unroll
        for (int r = 0; r < 4; ++r) {
            int row = i * 16 + qd * 4 + r;
#pragma unroll
            for (int j = 0; j < 2; ++j) {
                int col = nBase + w * 32 + j * 16 + c;
                Cp[row * N + col] = acc[i][j][r];
            }
        }
}

// ---------- 3. GRU gates (sums K-split partials, adds biases) ----------
__global__ __launch_bounds__(256) void k_gates(
    const float* __restrict__ Cg, const float* __restrict__ h0,
    const float* __restrict__ bih, const float* __restrict__ bhh,
    float* __restrict__ outv, unsigned short* __restrict__ X3b)
{
    int idx = blockIdx.x * 256 + threadIdx.x;
    int b = idx >> 10, h = idx & 1023;
    const float* g0 = Cg + b * 6144;
    const float* g1 = Cg + 393216 + b * 6144;
    float ir = g0[h] + g1[h] + bih[h];
    float iz = g0[h + 1024] + g1[h + 1024] + bih[h + 1024];
    float inn = g0[h + 2048] + g1[h + 2048] + bih[h + 2048];
    float hr = g0[h + 3072] + g1[h + 3072] + bhh[h];
    float hz = g0[h + 4096] + g1[h + 4096] + bhh[h + 1024];
    float hn = g0[h + 5120] + g1[h + 5120] + bhh[h + 2048];
    float r = 1.f / (1.f + __expf(-(ir + hr)));
    float z = 1.f / (1.f + __expf(-(iz + hz)));
    float n = tanh_fast(inn + r * hn);
    float o = (1.f - z) * n + z * h0[idx];
    outv[idx] = o;
    X3b[idx] = bf16_rne(o);
}

// ---------- 4. energy GEMM + FUSED context partial ----------
// Main loop = R2-exact (measured 99us). New epilogue: this block owns the 64
// annot rows whose sig-weights it just computed, so it also produces the
// unnormalized context partial sum_t sig(raw[t])*annots[t,:] by re-reading
// its own 131KB of annots (L2/L3-warm) row-major coalesced. This deletes the
// former k_ctxA kernel (a full 128MB HBM pass + one launch).
__global__ __launch_bounds__(256, 2) void k_attn(
    const float* __restrict__ annots, const unsigned short* __restrict__ Lconv,
    const unsigned short* __restrict__ Bbig, const float* __restrict__ pqP,
    const float* __restrict__ qb, const float* __restrict__ ebias,
    const float* __restrict__ vw, const int* __restrict__ mask,
    float* __restrict__ wsal, float* __restrict__ ctxP)
{
    __shared__ __align__(16) unsigned short As[2][64 * 32];    //  8 KB
    __shared__ __align__(16) unsigned short Bs[2][512 * 32];   // 64 KB
    __shared__ float red[4][64];
    __shared__ float sv[64];
    const int tid = threadIdx.x;
    const int btBase = blockIdx.x * 64;
    const int b = btBase >> 10;
    const int lane = tid & 63, w = tid >> 6;
    const int c = lane & 15, qd = lane >> 4;
    const int lr = lane >> 2;
    const int swzl = ((lane & 3) ^ ((lr >> 1) & 3)) * 8;
    const int arow = tid >> 2, alc = tid & 3;
    const int apofs = (alc ^ ((arow >> 1) & 3)) * 8;

    const f32x4 fz = {0.f, 0.f, 0.f, 0.f};
    f32x4 acc[4][8];
#pragma unroll
    for (int i = 0; i < 4; ++i)
#pragma unroll
        for (int j = 0; j < 8; ++j) acc[i][j] = fz;

    // per-thread source bases
    const float* aP = annots + (size_t)(btBase + arow) * 512 + alc * 8;
    const unsigned short* bP = Bbig + (size_t)(w * 16 + lr) * 544 + swzl;

    // ---- prologue: stage tile 0 into buffer 0 ----
#pragma unroll
    for (int s = 0; s < 8; ++s)
        ald16(bP + (size_t)s * 64 * 544, &Bs[0][s * 2048 + w * 512]);
    {
        float4 v0 = *(const float4*)(aP);
        float4 v1 = *(const float4*)(aP + 4);
        uint4 u;
        u.x = pk2(v0.x, v0.y); u.y = pk2(v0.z, v0.w);
        u.z = pk2(v1.x, v1.y); u.w = pk2(v1.z, v1.w);
        *(uint4*)&As[0][arow * 32 + apofs] = u;
    }
    __syncthreads();

    for (int kc = 0; kc < 17; ++kc) {
        const int cur = kc & 1, nxt = cur ^ 1;
        float4 v0n, v1n;
        // ---- issue next tile's loads (latency hides under this tile's compute)
        if (kc < 16) {
            const int k1 = (kc + 1) * 32;
#pragma unroll
            for (int s = 0; s < 8; ++s)
                ald16(bP + (size_t)s * 64 * 544 + k1, &Bs[nxt][s * 2048 + w * 512]);
            if (kc < 15) {
                v0n = *(const float4*)(aP + k1);
                v1n = *(const float4*)(aP + k1 + 4);
            } else {
                ald16(Lconv + (size_t)(btBase + w * 16 + lr) * 32 + swzl, &As[nxt][w * 512]);
            }
        }
        // ---- compute current tile
        const int rdoff = (qd ^ ((c >> 1) & 3)) * 8;
        bf16x8 af[4];
#pragma unroll
        for (int i = 0; i < 4; ++i) af[i] = *(const bf16x8*)&As[cur][(i * 16 + c) * 32 + rdoff];
        __builtin_amdgcn_s_setprio(1);
#pragma unroll
        for (int j = 0; j < 8; ++j) {
            bf16x8 bj = *(const bf16x8*)&Bs[cur][(w * 128 + j * 16 + c) * 32 + rdoff];
#pragma unroll
            for (int i = 0; i < 4; ++i) acc[i][j] = mfma16(af[i], bj, acc[i][j]);
        }
        __builtin_amdgcn_s_setprio(0);
        // ---- write-late: convert prefetched annots into As[nxt], then ONE barrier
        if (kc < 16) {
            if (kc < 15) {
                uint4 u;
                u.x = pk2(v0n.x, v0n.y); u.y = pk2(v0n.z, v0n.w);
                u.z = pk2(v1n.x, v1n.y); u.w = pk2(v1n.z, v1n.w);
                *(uint4*)&As[nxt][arow * 32 + apofs] = u;
            }
            __syncthreads();
        }
    }
    // ---- epilogue 1: raw alignment + sig into LDS ----
    float pe[8], vv[8];
#pragma unroll
    for (int j = 0; j < 8; ++j) {
        int colg = w * 128 + j * 16 + c;
        float s = qb[colg] + ebias[colg];
#pragma unroll
        for (int p = 0; p < 8; ++p) s += pqP[p * 32768 + b * 512 + colg];
        pe[j] = s;
        vv[j] = vw[colg];
    }
#pragma unroll
    for (int i = 0; i < 4; ++i)
#pragma unroll
        for (int r = 0; r < 4; ++r) {
            float p = 0.f;
#pragma unroll
            for (int j = 0; j < 8; ++j)
                p += vv[j] * tanh_fast(acc[i][j][r] + pe[j]);
            p += __shfl_xor(p, 1);
            p += __shfl_xor(p, 2);
            p += __shfl_xor(p, 4);
            p += __shfl_xor(p, 8);
            if (c == 0) red[w][i * 16 + qd * 4 + r] = p;
        }
    __syncthreads();
    if (tid < 64) {
        float raw = red[0][tid] + red[1][tid] + red[2][tid] + red[3][tid];
        wsal[btBase + tid] = raw;
        sv[tid] = (mask[btBase + tid] != 0) ? 1.f / (1.f + __expf(-raw)) : 0.f;
    }
    __syncthreads();
    // ---- epilogue 2: fused context partial for this block's 64 rows ----
    // wave w: rows w*16..w*16+15, lane covers cols lane*8..lane*8+7 (coalesced)
    {
        float cacc[8];
#pragma unroll
        for (int k = 0; k < 8; ++k) cacc[k] = 0.f;
        const float* ar = annots + (size_t)(btBase + w * 16) * 512 + lane * 8;
#pragma unroll 4
        for (int r2 = 0; r2 < 16; ++r2) {
            float s = sv[w * 16 + r2];
            float4 va = *(const float4*)(ar + (size_t)r2 * 512);
            float4 vb = *(const float4*)(ar + (size_t)r2 * 512 + 4);
            cacc[0] += s * va.x; cacc[1] += s * va.y;
            cacc[2] += s * va.z; cacc[3] += s * va.w;
            cacc[4] += s * vb.x; cacc[5] += s * vb.y;
            cacc[6] += s * vb.z; cacc[7] += s * vb.w;
        }
        // reduce across 4 waves via LDS (Bs is dead -> reuse as float scratch)
        float* cxf = (float*)&Bs[0][0];   // 4 x 512 floats = 8 KB
#pragma unroll
        for (int k = 0; k < 8; ++k) cxf[w * 512 + lane * 8 + k] = cacc[k];
        __syncthreads();
        const int chunk = blockIdx.x & 15;
        float* cp = ctxP + ((size_t)chunk * 64 + b) * 512;
        int d0 = tid * 2;
        cp[d0]     = cxf[d0]     + cxf[512 + d0]     + cxf[1024 + d0]     + cxf[1536 + d0];
        cp[d0 + 1] = cxf[d0 + 1] + cxf[512 + d0 + 1] + cxf[1024 + d0 + 1] + cxf[1536 + d0 + 1];
    }
}

// ---------- 5. normalize: alignment out + context reduce (16 chunks) ----------
__global__ __launch_bounds__(256) void k_ctxB(
    const float* __restrict__ wsal, const int* __restrict__ mask,
    const float* __restrict__ ctxP, float* __restrict__ out)
{
    __shared__ float sv[1024];
    __shared__ float wsum[4];
    const int b = blockIdx.x;
    const int tid = threadIdx.x;
    float lsum = 0.f;
#pragma unroll
    for (int p = 0; p < 4; ++p) {
        int t = p * 256 + tid;
        int bt = b * 1024 + t;
        float raw = wsal[bt];
        float s = (mask[bt] != 0) ? 1.f / (1.f + __expf(-raw)) : 0.f;
        sv[t] = s;
        lsum += s;
    }
    for (int off = 32; off > 0; off >>= 1) lsum += __shfl_xor(lsum, off);
    if ((tid & 63) == 0) wsum[tid >> 6] = lsum;
    __syncthreads();
    const float tot = wsum[0] + wsum[1] + wsum[2] + wsum[3];
    const float inv = 1.f / tot;
#pragma unroll
    for (int p = 0; p < 4; ++p) {
        int t = p * 256 + tid;
        out[98304 + b * 1024 + t] = sv[t] * inv;
    }
#pragma unroll
    for (int h = 0; h < 2; ++h) {
        int d = h * 256 + tid;
        float csum = 0.f;
#pragma unroll
        for (int tc = 0; tc < 16; ++tc)
            csum += ctxP[((size_t)tc * 64 + b) * 512 + d];
        out[65536 + b * 512 + d] = csum * inv;
    }
}

extern "C" void kernel_launch(void* const* d_in, const int* in_sizes, int n_in,
                              void* d_out, int out_size, void* d_ws, size_t ws_size,
                              hipStream_t stream) {
    const float* memory    = (const float*)d_in[0];
    const float* context   = (const float*)d_in[1];
    const float* rnn_state = (const float*)d_in[2];
    const float* annots    = (const float*)d_in[3];
    const float* atten     = (const float*)d_in[4];
    const int*   mask      = (const int*)d_in[5];
    const float* W_ih   = (const float*)d_in[7];
    const float* W_hh   = (const float*)d_in[8];
    const float* b_ih   = (const float*)d_in[9];
    const float* b_hh   = (const float*)d_in[10];
    const float* conv_w = (const float*)d_in[11];
    const float* loc_w  = (const float*)d_in[12];
    const float* loc_b  = (const float*)d_in[13];
    const float* q_w    = (const float*)d_in[14];
    const float* q_b    = (const float*)d_in[15];
    const float* a_w    = (const float*)d_in[16];
    const float* a_b    = (const float*)d_in[17];
    const float* v_w    = (const float*)d_in[18];
    float* out = (float*)d_out;

    char* w8 = (char*)d_ws;
    unsigned short* Lconv = (unsigned short*)(w8 + 0);         //  4,194,304
    unsigned short* Bbig  = (unsigned short*)(w8 + 4194304);   //    557,056
    unsigned short* Wihb  = (unsigned short*)(w8 + 4751360);   //  6,291,456
    unsigned short* Whhb  = (unsigned short*)(w8 + 11042816);  //  6,291,456
    unsigned short* qwb   = (unsigned short*)(w8 + 17334272);  //  1,048,576
    unsigned short* X1b   = (unsigned short*)(w8 + 18382848);  //    131,072
    unsigned short* X2b   = (unsigned short*)(w8 + 18513920);  //    131,072
    unsigned short* X3b   = (unsigned short*)(w8 + 18644992);  //    131,072
    float*          Cgru  = (float*)(w8 + 18776064);           //  3,145,728 (2 K-split partials)
    // pqP (8 partials, 1MB) aliases Cgru (dead after k_gates).
    // ctxP (16 x 64 x 512 f32 = 2MB) aliases Wihb (dead after GRU gemm).
    float*          pqP   = (float*)(w8 + 18776064);           //  1,048,576
    float*          ctxP  = (float*)(w8 + 4751360);            //  2,097,152
    float*          wsal  = (float*)(w8 + 19824640);           //    262,144
    float*          ebias = (float*)(w8 + 21921792);           //      2,048

    k_prep<<<NCVT + 512, 256, 0, stream>>>(W_ih, W_hh, q_w, rnn_state, memory, context,
                                           a_w, loc_w, a_b, loc_b, atten, conv_w,
                                           Wihb, Whhb, qwb, X2b, X1b, Bbig, ebias, Lconv);
    // GRU: N=6144 (gi|gh), 48 N-tiles x K-split2 = 96 blocks
    k_gemm_ks<<<96, 256, 0, stream>>>(X1b, X2b, Wihb, Whhb, Cgru, 6144, 48, 3072, 1024, 512);
    k_gates<<<256, 256, 0, stream>>>(Cgru, rnn_state, b_ih, b_hh, out, X3b);
    // pq: N=512, 4 N-tiles x K-split8 (Klen=128) = 32 blocks
    k_gemm_ks<<<32, 256, 0, stream>>>(X3b, X3b, qwb, qwb, pqP, 512, 4, 0x40000000, 1024, 128);
    k_attn<<<1024, 256, 0, stream>>>(annots, Lconv, Bbig, pqP, q_b, ebias, v_w, mask, wsal, ctxP);
    k_ctxB<<<64, 256, 0, stream>>>(wsal, mask, ctxP, out);
}